// Round 3
// baseline (174.590 us; speedup 1.0000x reference)
//
#include <hip/hip_runtime.h>
#include <math.h>

// Problem constants (fixed by the reference file)
#define B_     32
#define T_     2048
#define H_     1024
#define WIDTH_ 32        // max(32, 45000 // (1024+512)) = 32
#define TOTAL_ 512       // K_C + K_E
#define TOPK_  8

#define ROWS_PER_BLK 32              // T rows per add-block
#define CHUNKS_ (T_ / ROWS_PER_BLK)  // 64 blocks per batch

// ---------------------------------------------------------------------------
// Kernel 1: per-batch-row head computation -> 32 x 1024 update table in ws
// ---------------------------------------------------------------------------
__global__ __launch_bounds__(256) void head_kernel(
    const float* __restrict__ hidden,   // (B, T, H)
    const float* __restrict__ W1,       // (H, WIDTH)
    const float* __restrict__ b1,       // (WIDTH)
    const float* __restrict__ W2,       // (WIDTH, TOTAL)
    const float* __restrict__ b2,       // (TOTAL)
    const float* __restrict__ Dc,       // (256, H)
    const float* __restrict__ De,       // (256, H)
    const float* __restrict__ temp,     // scalar
    float* __restrict__ upd)            // (B, H) output update table
{
    __shared__ float s_cls[H_];
    __shared__ float s_h1[WIDTH_];
    __shared__ float s_logits[TOTAL_];
    __shared__ float s_red[256];
    __shared__ int   s_redi[256];
    __shared__ float s_u[H_];
    __shared__ int   s_tidx[TOPK_];
    __shared__ float s_tval[TOPK_];

    const int b = blockIdx.x;
    const int t = threadIdx.x;

    // ---- load cls = hidden[b, 0, :] into LDS ----
    const float* cls = hidden + (size_t)b * T_ * H_;
    for (int h = t; h < H_; h += 256) s_cls[h] = cls[h];
    __syncthreads();

    // ---- h1 = relu(cls @ W1 + b1): 32 groups of 8 threads ----
    {
        const int j    = t >> 3;   // 0..31 output index
        const int lane = t & 7;
        float acc = 0.f;
        for (int h = lane; h < H_; h += 8)
            acc += s_cls[h] * W1[h * WIDTH_ + j];
        // reduce across the 8 lanes of the group (contiguous within wave)
        for (int off = 4; off >= 1; off >>= 1)
            acc += __shfl_down(acc, off, 8);
        if (lane == 0) s_h1[j] = fmaxf(acc + b1[j], 0.f);
    }
    __syncthreads();

    // ---- logits = (h1 @ W2 + b2) / |temp| ----
    const float invT = 1.0f / fabsf(temp[0]);
    for (int i = t; i < TOTAL_; i += 256) {
        float acc = b2[i];
        #pragma unroll
        for (int j = 0; j < WIDTH_; j++)
            acc += s_h1[j] * W2[j * TOTAL_ + i];
        s_logits[i] = acc * invT;
    }
    __syncthreads();

    // ---- softmax statistics: global max, then Z = sum(exp(l - max)) ----
    float m = -INFINITY;
    for (int i = t; i < TOTAL_; i += 256) m = fmaxf(m, s_logits[i]);
    s_red[t] = m;
    __syncthreads();
    for (int s = 128; s >= 1; s >>= 1) {
        if (t < s) s_red[t] = fmaxf(s_red[t], s_red[t + s]);
        __syncthreads();
    }
    const float gmax = s_red[0];
    __syncthreads();

    float sum = 0.f;
    for (int i = t; i < TOTAL_; i += 256) sum += expf(s_logits[i] - gmax);
    s_red[t] = sum;
    __syncthreads();
    for (int s = 128; s >= 1; s >>= 1) {
        if (t < s) s_red[t] += s_red[t + s];
        __syncthreads();
    }
    const float invZ = 1.0f / s_red[0];
    __syncthreads();

    // ---- top-8 by logit (== top-8 by prob), tie-break to lower index ----
    for (int k = 0; k < TOPK_; k++) {
        float bv = -INFINITY;
        int   bi = 0x7fffffff;
        for (int i = t; i < TOTAL_; i += 256) {
            float v = s_logits[i];
            if (v > bv) { bv = v; bi = i; }   // strict > keeps lower index
        }
        s_red[t]  = bv;
        s_redi[t] = bi;
        __syncthreads();
        for (int s = 128; s >= 1; s >>= 1) {
            if (t < s) {
                float ov = s_red[t + s]; int oi = s_redi[t + s];
                if (ov > s_red[t] || (ov == s_red[t] && oi < s_redi[t])) {
                    s_red[t] = ov; s_redi[t] = oi;
                }
            }
            __syncthreads();
        }
        if (t == 0) {
            int idx = s_redi[0];
            s_tidx[k] = idx;
            s_tval[k] = expf(s_red[0] - gmax) * invZ;  // prob value
            s_logits[idx] = -INFINITY;                 // remove from pool
        }
        __syncthreads();
    }

    // ---- update = sum_k prob_k * dict[idx_k, :] ----
    for (int h = t; h < H_; h += 256) {
        float acc = 0.f;
        #pragma unroll
        for (int k = 0; k < TOPK_; k++) {
            const int idx = s_tidx[k];
            const float* row = (idx < 256) ? (Dc + (size_t)idx * H_)
                                           : (De + (size_t)(idx - 256) * H_);
            acc += s_tval[k] * row[h];
        }
        s_u[h] = acc;
    }
    __syncthreads();

    // ---- L2 norm over 1024 elements ----
    float ss = 0.f;
    for (int h = t; h < H_; h += 256) ss += s_u[h] * s_u[h];
    s_red[t] = ss;
    __syncthreads();
    for (int s = 128; s >= 1; s >>= 1) {
        if (t < s) s_red[t] += s_red[t + s];
        __syncthreads();
    }
    const float norm = sqrtf(s_red[0]);
    // final scale: / (norm + 1e-12) / sqrt(H)
    const float scale = 1.0f / ((norm + 1e-12f) * 32.0f);
    for (int h = t; h < H_; h += 256)
        upd[(size_t)b * H_ + h] = s_u[h] * scale;
}

// ---------------------------------------------------------------------------
// Kernel 2: out = hidden + upd[b] broadcast over T.
// One block = one batch b, one 32-row slab. Thread t holds upd float4 #t in a
// register for the whole block; rows are contiguous 4 KB coalesced streams.
// ---------------------------------------------------------------------------
__global__ __launch_bounds__(256) void add_kernel(
    const float* __restrict__ hidden,
    const float* __restrict__ upd,      // (B, H)
    float* __restrict__ out)
{
    const int chunk = blockIdx.x;       // 0..CHUNKS_-1
    const int b     = blockIdx.y;       // 0..B_-1
    const int t     = threadIdx.x;      // 0..255 -> one float4 of H

    // update vector element for this thread, loaded ONCE
    const float4 uv = ((const float4*)upd)[b * (H_ / 4) + t];

    // base float4 index of this slab: batch b, row chunk*32, float4 t
    size_t idx = ((size_t)b * T_ + (size_t)chunk * ROWS_PER_BLK) * (H_ / 4) + t;

    const float4* __restrict__ h4 = (const float4*)hidden;
    float4* __restrict__ o4 = (float4*)out;

    #pragma unroll 4
    for (int r = 0; r < ROWS_PER_BLK; r++) {
        float4 hv = h4[idx];
        hv.x += uv.x; hv.y += uv.y; hv.z += uv.z; hv.w += uv.w;
        o4[idx] = hv;
        idx += (H_ / 4);                // next row, +1 KB in float4 units
    }
}

// ---------------------------------------------------------------------------
extern "C" void kernel_launch(void* const* d_in, const int* in_sizes, int n_in,
                              void* d_out, int out_size, void* d_ws, size_t ws_size,
                              hipStream_t stream) {
    const float* hidden = (const float*)d_in[0];
    const float* W1     = (const float*)d_in[1];
    const float* b1     = (const float*)d_in[2];
    const float* W2     = (const float*)d_in[3];
    const float* b2     = (const float*)d_in[4];
    const float* Dc     = (const float*)d_in[5];
    const float* De     = (const float*)d_in[6];
    const float* temp   = (const float*)d_in[7];

    float* out = (float*)d_out;
    float* upd = (float*)d_ws;   // 32*1024*4 = 128 KB scratch

    head_kernel<<<B_, 256, 0, stream>>>(hidden, W1, b1, W2, b2, Dc, De, temp, upd);

    dim3 grid(CHUNKS_, B_);      // 64 x 32 = 2048 blocks
    add_kernel<<<grid, 256, 0, stream>>>(hidden, upd, out);
}

// Round 4
// 114.356 us; speedup vs baseline: 1.5267x; 1.5267x over previous
//
#include <hip/hip_runtime.h>
#include <math.h>

typedef float f32x4 __attribute__((ext_vector_type(4)));

// Problem constants (fixed by the reference file)
#define B_     32
#define T_     2048
#define H_     1024
#define WIDTH_ 32        // max(32, 45000 // (1024+512)) = 32
#define TOTAL_ 512       // K_C + K_E
#define TOPK_  8

#define ROWS_PER_BLK 32              // T rows per add-block
#define CHUNKS_ (T_ / ROWS_PER_BLK)  // 64 blocks per batch

// ---------------------------------------------------------------------------
// Kernel 1: head computation. ONE WAVE (64 lanes) per batch row, zero barriers
// after the cls stage: all reductions are __shfl_xor butterflies.
// ---------------------------------------------------------------------------
__global__ __launch_bounds__(64) void head_kernel(
    const float* __restrict__ hidden,   // (B, T, H)
    const float* __restrict__ W1,       // (H, WIDTH)
    const float* __restrict__ b1,       // (WIDTH)
    const float* __restrict__ W2,       // (WIDTH, TOTAL)
    const float* __restrict__ b2,       // (TOTAL)
    const float* __restrict__ Dc,       // (256, H)
    const float* __restrict__ De,       // (256, H)
    const float* __restrict__ temp,     // scalar
    float* __restrict__ upd)            // (B, H) update table
{
    __shared__ float s_cls[H_];
    const int b = blockIdx.x;
    const int l = threadIdx.x;          // 0..63

    // ---- stage cls = hidden[b,0,:] (4 KB) into LDS, coalesced float4 ----
    const f32x4* cls4 = (const f32x4*)(hidden + (size_t)b * T_ * H_);
    f32x4* sc4 = (f32x4*)s_cls;
    #pragma unroll
    for (int q = 0; q < 4; q++) sc4[l + 64*q] = cls4[l + 64*q];
    __syncthreads();                    // single wave: compiles to waitcnt

    // ---- h1 = relu(cls @ W1 + b1) ----
    // W1 flat as 8192 float4; element i = l + 64*it -> h = i>>3, col-quad = i&7
    const f32x4* W14 = (const f32x4*)W1;
    float a0 = 0.f, a1 = 0.f, a2 = 0.f, a3 = 0.f;
    #pragma unroll 8
    for (int it = 0; it < 128; it++) {
        const int i = l + 64*it;
        const f32x4 f = W14[i];
        const float c = s_cls[i >> 3];
        a0 += c * f[0]; a1 += c * f[1]; a2 += c * f[2]; a3 += c * f[3];
    }
    // reduce the 8 lanes sharing the same col-quad (l, l^8, l^16, l^32 ...)
    #pragma unroll
    for (int off = 8; off <= 32; off <<= 1) {
        a0 += __shfl_xor(a0, off);
        a1 += __shfl_xor(a1, off);
        a2 += __shfl_xor(a2, off);
        a3 += __shfl_xor(a3, off);
    }
    // lane group g = l&7 now holds dot(cls, W1[:, 4g..4g+3]) in a0..a3

    const float invT = 1.0f / fabsf(temp[0]);

    // ---- logits: lane l owns i = 8l .. 8l+7 ----
    const f32x4* b24 = (const f32x4*)b2;
    f32x4 lgA = b24[2*l];
    f32x4 lgB = b24[2*l + 1];
    #pragma unroll
    for (int j = 0; j < WIDTH_; j++) {
        const int  qc = j & 3;
        const float aq = (qc == 0) ? a0 : (qc == 1) ? a1 : (qc == 2) ? a2 : a3;
        float hj = __shfl(aq, j >> 2);          // lane (j>>2) holds quad j&3
        hj = fmaxf(hj + b1[j], 0.f);            // bias + relu (same in all lanes)
        const f32x4* w2r = (const f32x4*)(W2 + (size_t)j * TOTAL_);
        lgA += hj * w2r[2*l];
        lgB += hj * w2r[2*l + 1];
    }
    lgA *= invT; lgB *= invT;

    float lv[8] = { lgA[0], lgA[1], lgA[2], lgA[3], lgB[0], lgB[1], lgB[2], lgB[3] };

    // ---- softmax stats (wave butterflies) ----
    float m = lv[0];
    #pragma unroll
    for (int q = 1; q < 8; q++) m = fmaxf(m, lv[q]);
    #pragma unroll
    for (int off = 32; off >= 1; off >>= 1) m = fmaxf(m, __shfl_xor(m, off));
    float Z = 0.f;
    #pragma unroll
    for (int q = 0; q < 8; q++) Z += expf(lv[q] - m);
    #pragma unroll
    for (int off = 32; off >= 1; off >>= 1) Z += __shfl_xor(Z, off);
    const float invZ = 1.0f / Z;

    // ---- top-8 (by logit == by prob), tie-break to lower index ----
    int   tidx[TOPK_];
    float tp[TOPK_];
    #pragma unroll
    for (int k = 0; k < TOPK_; k++) {
        float bv = lv[0]; int bq = 0;
        #pragma unroll
        for (int q = 1; q < 8; q++)
            if (lv[q] > bv) { bv = lv[q]; bq = q; }   // strict > keeps low idx
        int bi = l * 8 + bq;
        #pragma unroll
        for (int off = 32; off >= 1; off >>= 1) {
            const float ov = __shfl_xor(bv, off);
            const int   oi = __shfl_xor(bi, off);
            if (ov > bv || (ov == bv && oi < bi)) { bv = ov; bi = oi; }
        }
        tidx[k] = bi;
        tp[k]   = expf(bv - m) * invZ;
        // winner lane clears its slot (static indices only -> stays in VGPRs)
        if ((bi >> 3) == l) {
            const int wq = bi & 7;
            #pragma unroll
            for (int q = 0; q < 8; q++) if (q == wq) lv[q] = -INFINITY;
        }
    }

    // ---- update = sum_k p_k * dict[idx_k,:], coalesced float4 ----
    f32x4 u0 = {0.f,0.f,0.f,0.f}, u1 = u0, u2 = u0, u3 = u0;
    #pragma unroll
    for (int k = 0; k < TOPK_; k++) {
        const float* row = (tidx[k] < 256) ? (Dc + (size_t)tidx[k] * H_)
                                           : (De + (size_t)(tidx[k] - 256) * H_);
        const f32x4* r4 = (const f32x4*)row;
        const float p = tp[k];
        u0 += p * r4[l];
        u1 += p * r4[l + 64];
        u2 += p * r4[l + 128];
        u3 += p * r4[l + 192];
    }

    // ---- L2 norm + final scale ----
    float ss = u0[0]*u0[0] + u0[1]*u0[1] + u0[2]*u0[2] + u0[3]*u0[3]
             + u1[0]*u1[0] + u1[1]*u1[1] + u1[2]*u1[2] + u1[3]*u1[3]
             + u2[0]*u2[0] + u2[1]*u2[1] + u2[2]*u2[2] + u2[3]*u2[3]
             + u3[0]*u3[0] + u3[1]*u3[1] + u3[2]*u3[2] + u3[3]*u3[3];
    #pragma unroll
    for (int off = 32; off >= 1; off >>= 1) ss += __shfl_xor(ss, off);
    const float scale = 1.0f / ((sqrtf(ss) + 1e-12f) * 32.0f);  // *1/sqrt(1024)

    f32x4* up4 = (f32x4*)(upd + (size_t)b * H_);
    up4[l]       = u0 * scale;
    up4[l + 64]  = u1 * scale;
    up4[l + 128] = u2 * scale;
    up4[l + 192] = u3 * scale;
}

// ---------------------------------------------------------------------------
// Kernel 2: out = hidden + upd[b].  Slab per block; 8-deep explicit
// load/store pipeline with nontemporal (L2-bypass) accesses on both streams.
// ---------------------------------------------------------------------------
__global__ __launch_bounds__(256) void add_kernel(
    const f32x4* __restrict__ h4,
    const f32x4* __restrict__ upd4,     // (B, H/4)
    f32x4* __restrict__ o4)
{
    const int chunk = blockIdx.x;       // 0..CHUNKS_-1
    const int b     = blockIdx.y;       // 0..B_-1
    const int t     = threadIdx.x;      // 0..255 -> one float4 of H

    const f32x4 uv = upd4[b * (H_/4) + t];   // loaded once, L2-resident table

    size_t idx = ((size_t)b * T_ + (size_t)chunk * ROWS_PER_BLK) * (H_/4) + t;

    #pragma unroll
    for (int o = 0; o < ROWS_PER_BLK / 8; o++) {
        // 8 independent loads in flight before any store
        f32x4 v0 = __builtin_nontemporal_load(&h4[idx         ]);
        f32x4 v1 = __builtin_nontemporal_load(&h4[idx +  1*256]);
        f32x4 v2 = __builtin_nontemporal_load(&h4[idx +  2*256]);
        f32x4 v3 = __builtin_nontemporal_load(&h4[idx +  3*256]);
        f32x4 v4 = __builtin_nontemporal_load(&h4[idx +  4*256]);
        f32x4 v5 = __builtin_nontemporal_load(&h4[idx +  5*256]);
        f32x4 v6 = __builtin_nontemporal_load(&h4[idx +  6*256]);
        f32x4 v7 = __builtin_nontemporal_load(&h4[idx +  7*256]);
        v0 += uv; v1 += uv; v2 += uv; v3 += uv;
        v4 += uv; v5 += uv; v6 += uv; v7 += uv;
        __builtin_nontemporal_store(v0, &o4[idx         ]);
        __builtin_nontemporal_store(v1, &o4[idx +  1*256]);
        __builtin_nontemporal_store(v2, &o4[idx +  2*256]);
        __builtin_nontemporal_store(v3, &o4[idx +  3*256]);
        __builtin_nontemporal_store(v4, &o4[idx +  4*256]);
        __builtin_nontemporal_store(v5, &o4[idx +  5*256]);
        __builtin_nontemporal_store(v6, &o4[idx +  6*256]);
        __builtin_nontemporal_store(v7, &o4[idx +  7*256]);
        idx += 8 * 256;
    }
}

// ---------------------------------------------------------------------------
extern "C" void kernel_launch(void* const* d_in, const int* in_sizes, int n_in,
                              void* d_out, int out_size, void* d_ws, size_t ws_size,
                              hipStream_t stream) {
    const float* hidden = (const float*)d_in[0];
    const float* W1     = (const float*)d_in[1];
    const float* b1     = (const float*)d_in[2];
    const float* W2     = (const float*)d_in[3];
    const float* b2     = (const float*)d_in[4];
    const float* Dc     = (const float*)d_in[5];
    const float* De     = (const float*)d_in[6];
    const float* temp   = (const float*)d_in[7];

    float* out = (float*)d_out;
    float* upd = (float*)d_ws;   // 32*1024*4 = 128 KB scratch

    head_kernel<<<B_, 64, 0, stream>>>(hidden, W1, b1, W2, b2, Dc, De, temp, upd);

    dim3 grid(CHUNKS_, B_);      // 64 x 32 = 2048 blocks
    add_kernel<<<grid, 256, 0, stream>>>((const f32x4*)hidden, (const f32x4*)upd,
                                         (f32x4*)out);
}

// Round 5
// 109.744 us; speedup vs baseline: 1.5909x; 1.0420x over previous
//
#include <hip/hip_runtime.h>
#include <math.h>

typedef float f32x4 __attribute__((ext_vector_type(4)));

// Problem constants (fixed by the reference file)
#define B_     32
#define T_     2048
#define H_     1024
#define WIDTH_ 32        // max(32, 45000 // (1024+512)) = 32
#define TOTAL_ 512       // K_C + K_E
#define TOPK_  8

#define ROWS_PER_BLK 32              // T rows per add-block
#define CHUNKS_ (T_ / ROWS_PER_BLK)  // 64 blocks per batch

// ---------------------------------------------------------------------------
// Kernel 1: head computation. ONE WAVE (64 lanes) per batch row, zero barriers
// after the cls stage: all reductions are __shfl_xor butterflies.
// (unchanged from round 4 — proven correct, ~5-8 us)
// ---------------------------------------------------------------------------
__global__ __launch_bounds__(64) void head_kernel(
    const float* __restrict__ hidden,   // (B, T, H)
    const float* __restrict__ W1,       // (H, WIDTH)
    const float* __restrict__ b1,       // (WIDTH)
    const float* __restrict__ W2,       // (WIDTH, TOTAL)
    const float* __restrict__ b2,       // (TOTAL)
    const float* __restrict__ Dc,       // (256, H)
    const float* __restrict__ De,       // (256, H)
    const float* __restrict__ temp,     // scalar
    float* __restrict__ upd)            // (B, H) update table
{
    __shared__ float s_cls[H_];
    const int b = blockIdx.x;
    const int l = threadIdx.x;          // 0..63

    // ---- stage cls = hidden[b,0,:] (4 KB) into LDS, coalesced float4 ----
    const f32x4* cls4 = (const f32x4*)(hidden + (size_t)b * T_ * H_);
    f32x4* sc4 = (f32x4*)s_cls;
    #pragma unroll
    for (int q = 0; q < 4; q++) sc4[l + 64*q] = cls4[l + 64*q];
    __syncthreads();                    // single wave: compiles to waitcnt

    // ---- h1 = relu(cls @ W1 + b1) ----
    // W1 flat as 8192 float4; element i = l + 64*it -> h = i>>3, col-quad = i&7
    const f32x4* W14 = (const f32x4*)W1;
    float a0 = 0.f, a1 = 0.f, a2 = 0.f, a3 = 0.f;
    #pragma unroll 8
    for (int it = 0; it < 128; it++) {
        const int i = l + 64*it;
        const f32x4 f = W14[i];
        const float c = s_cls[i >> 3];
        a0 += c * f[0]; a1 += c * f[1]; a2 += c * f[2]; a3 += c * f[3];
    }
    // reduce the 8 lanes sharing the same col-quad (l, l^8, l^16, l^32 ...)
    #pragma unroll
    for (int off = 8; off <= 32; off <<= 1) {
        a0 += __shfl_xor(a0, off);
        a1 += __shfl_xor(a1, off);
        a2 += __shfl_xor(a2, off);
        a3 += __shfl_xor(a3, off);
    }
    // lane group g = l&7 now holds dot(cls, W1[:, 4g..4g+3]) in a0..a3

    const float invT = 1.0f / fabsf(temp[0]);

    // ---- logits: lane l owns i = 8l .. 8l+7 ----
    const f32x4* b24 = (const f32x4*)b2;
    f32x4 lgA = b24[2*l];
    f32x4 lgB = b24[2*l + 1];
    #pragma unroll
    for (int j = 0; j < WIDTH_; j++) {
        const int  qc = j & 3;
        const float aq = (qc == 0) ? a0 : (qc == 1) ? a1 : (qc == 2) ? a2 : a3;
        float hj = __shfl(aq, j >> 2);          // lane (j>>2) holds quad j&3
        hj = fmaxf(hj + b1[j], 0.f);            // bias + relu (same in all lanes)
        const f32x4* w2r = (const f32x4*)(W2 + (size_t)j * TOTAL_);
        lgA += hj * w2r[2*l];
        lgB += hj * w2r[2*l + 1];
    }
    lgA *= invT; lgB *= invT;

    float lv[8] = { lgA[0], lgA[1], lgA[2], lgA[3], lgB[0], lgB[1], lgB[2], lgB[3] };

    // ---- softmax stats (wave butterflies) ----
    float m = lv[0];
    #pragma unroll
    for (int q = 1; q < 8; q++) m = fmaxf(m, lv[q]);
    #pragma unroll
    for (int off = 32; off >= 1; off >>= 1) m = fmaxf(m, __shfl_xor(m, off));
    float Z = 0.f;
    #pragma unroll
    for (int q = 0; q < 8; q++) Z += expf(lv[q] - m);
    #pragma unroll
    for (int off = 32; off >= 1; off >>= 1) Z += __shfl_xor(Z, off);
    const float invZ = 1.0f / Z;

    // ---- top-8 (by logit == by prob), tie-break to lower index ----
    int   tidx[TOPK_];
    float tp[TOPK_];
    #pragma unroll
    for (int k = 0; k < TOPK_; k++) {
        float bv = lv[0]; int bq = 0;
        #pragma unroll
        for (int q = 1; q < 8; q++)
            if (lv[q] > bv) { bv = lv[q]; bq = q; }   // strict > keeps low idx
        int bi = l * 8 + bq;
        #pragma unroll
        for (int off = 32; off >= 1; off >>= 1) {
            const float ov = __shfl_xor(bv, off);
            const int   oi = __shfl_xor(bi, off);
            if (ov > bv || (ov == bv && oi < bi)) { bv = ov; bi = oi; }
        }
        tidx[k] = bi;
        tp[k]   = expf(bv - m) * invZ;
        // winner lane clears its slot (static indices only -> stays in VGPRs)
        if ((bi >> 3) == l) {
            const int wq = bi & 7;
            #pragma unroll
            for (int q = 0; q < 8; q++) if (q == wq) lv[q] = -INFINITY;
        }
    }

    // ---- update = sum_k p_k * dict[idx_k,:], coalesced float4 ----
    f32x4 u0 = {0.f,0.f,0.f,0.f}, u1 = u0, u2 = u0, u3 = u0;
    #pragma unroll
    for (int k = 0; k < TOPK_; k++) {
        const float* row = (tidx[k] < 256) ? (Dc + (size_t)tidx[k] * H_)
                                           : (De + (size_t)(tidx[k] - 256) * H_);
        const f32x4* r4 = (const f32x4*)row;
        const float p = tp[k];
        u0 += p * r4[l];
        u1 += p * r4[l + 64];
        u2 += p * r4[l + 128];
        u3 += p * r4[l + 192];
    }

    // ---- L2 norm + final scale ----
    float ss = u0[0]*u0[0] + u0[1]*u0[1] + u0[2]*u0[2] + u0[3]*u0[3]
             + u1[0]*u1[0] + u1[1]*u1[1] + u1[2]*u1[2] + u1[3]*u1[3]
             + u2[0]*u2[0] + u2[1]*u2[1] + u2[2]*u2[2] + u2[3]*u2[3]
             + u3[0]*u3[0] + u3[1]*u3[1] + u3[2]*u3[2] + u3[3]*u3[3];
    #pragma unroll
    for (int off = 32; off >= 1; off >>= 1) ss += __shfl_xor(ss, off);
    const float scale = 1.0f / ((sqrtf(ss) + 1e-12f) * 32.0f);  // *1/sqrt(1024)

    f32x4* up4 = (f32x4*)(upd + (size_t)b * H_);
    up4[l]       = u0 * scale;
    up4[l + 64]  = u1 * scale;
    up4[l + 128] = u2 * scale;
    up4[l + 192] = u3 * scale;
}

// ---------------------------------------------------------------------------
// Kernel 2: out = hidden + upd[b].  Identical structure to round 4, single
// variable changed: LOADS ARE TEMPORAL (hidden = 256 MB = LLC size, re-read
// every replay -> allow LLC residency), stores stay nontemporal (write-once
// stream must not thrash the LLC).
// ---------------------------------------------------------------------------
__global__ __launch_bounds__(256) void add_kernel(
    const f32x4* __restrict__ h4,
    const f32x4* __restrict__ upd4,     // (B, H/4)
    f32x4* __restrict__ o4)
{
    const int chunk = blockIdx.x;       // 0..CHUNKS_-1
    const int b     = blockIdx.y;       // 0..B_-1
    const int t     = threadIdx.x;      // 0..255 -> one float4 of H

    const f32x4 uv = upd4[b * (H_/4) + t];   // loaded once, L2-resident table

    size_t idx = ((size_t)b * T_ + (size_t)chunk * ROWS_PER_BLK) * (H_/4) + t;

    #pragma unroll
    for (int o = 0; o < ROWS_PER_BLK / 8; o++) {
        // 8 independent loads in flight before any store
        f32x4 v0 = h4[idx         ];
        f32x4 v1 = h4[idx +  1*256];
        f32x4 v2 = h4[idx +  2*256];
        f32x4 v3 = h4[idx +  3*256];
        f32x4 v4 = h4[idx +  4*256];
        f32x4 v5 = h4[idx +  5*256];
        f32x4 v6 = h4[idx +  6*256];
        f32x4 v7 = h4[idx +  7*256];
        v0 += uv; v1 += uv; v2 += uv; v3 += uv;
        v4 += uv; v5 += uv; v6 += uv; v7 += uv;
        __builtin_nontemporal_store(v0, &o4[idx         ]);
        __builtin_nontemporal_store(v1, &o4[idx +  1*256]);
        __builtin_nontemporal_store(v2, &o4[idx +  2*256]);
        __builtin_nontemporal_store(v3, &o4[idx +  3*256]);
        __builtin_nontemporal_store(v4, &o4[idx +  4*256]);
        __builtin_nontemporal_store(v5, &o4[idx +  5*256]);
        __builtin_nontemporal_store(v6, &o4[idx +  6*256]);
        __builtin_nontemporal_store(v7, &o4[idx +  7*256]);
        idx += 8 * 256;
    }
}

// ---------------------------------------------------------------------------
extern "C" void kernel_launch(void* const* d_in, const int* in_sizes, int n_in,
                              void* d_out, int out_size, void* d_ws, size_t ws_size,
                              hipStream_t stream) {
    const float* hidden = (const float*)d_in[0];
    const float* W1     = (const float*)d_in[1];
    const float* b1     = (const float*)d_in[2];
    const float* W2     = (const float*)d_in[3];
    const float* b2     = (const float*)d_in[4];
    const float* Dc     = (const float*)d_in[5];
    const float* De     = (const float*)d_in[6];
    const float* temp   = (const float*)d_in[7];

    float* out = (float*)d_out;
    float* upd = (float*)d_ws;   // 32*1024*4 = 128 KB scratch

    head_kernel<<<B_, 64, 0, stream>>>(hidden, W1, b1, W2, b2, Dc, De, temp, upd);

    dim3 grid(CHUNKS_, B_);      // 64 x 32 = 2048 blocks
    add_kernel<<<grid, 256, 0, stream>>>((const f32x4*)hidden, (const f32x4*)upd,
                                         (f32x4*)out);
}